// Round 9
// baseline (92.820 us; speedup 1.0000x reference)
//
#include <hip/hip_runtime.h>
#include <hip/hip_cooperative_groups.h>
#include <math.h>

namespace cg = cooperative_groups;

#define B 8
#define H 384
#define W 384
#define HW (H*W)
#define NTOT (B*HW)
#define INF_I 10000
#define NBLK 256           // cooperative grid: 256 blocks x 768 thr (>=1/CU)
#define NFB 192            // phase-A blocks doing fused BCE/dice/sumA
#define NVB 48             // phase-A blocks doing vertical EDT (192..239)

// ws layout (bytes):
//   part2 @ 0      : NFB*25 doubles (38400 B)  fused partials
//   part  @ 40960  : NBLK doubles   (2048 B)   phase-B block partials
//   g2u   @ 65536  : NTOT uint      (dpos | dneg<<16)
//   sumA  @ 4784128: HW float       (sum_b |p - t|)

__global__ __launch_bounds__(768, 1) void k_coop(const float* __restrict__ pred,
                                                 const int* __restrict__ tgt,
                                                 float* __restrict__ sumA,
                                                 double* __restrict__ part2,
                                                 unsigned* __restrict__ g2u,
                                                 double* __restrict__ part,
                                                 float* __restrict__ out) {
    cg::grid_group grid = cg::this_grid();
    __shared__ float lds[12][25];
    __shared__ unsigned bmsh[12][64];
    __shared__ float lfp[12][412], lfn[12][412];
    __shared__ double wpart[12];
    __shared__ double sval[25];
    __shared__ double sl2[4];
    int tid = threadIdx.x, bid = blockIdx.x;

    // ================= phase A =================
    if (bid < NFB) {
        // ---- fused BCE + dice partials + sumA: one pixel/thread, 8 batches ----
        int pix = bid * 768 + tid;
        float vals[25];                    // 0=bce, 1+b=p, 9+b=p*t, 17+b=t
        float sA = 0.f, bce = 0.f;
#pragma unroll
        for (int b = 0; b < 8; ++b) {
            float x = pred[b * HW + pix];
            int t = tgt[b * HW + pix];
            float e = expf(-fabsf(x));
            float r = 1.f / (1.f + e);
            float p = (x >= 0.f) ? r : 1.f - r;                // stable sigmoid
            bce += fmaxf(x, 0.f) + log1pf(e) - x * (float)t;   // softplus - x*t
            vals[1 + b] = p;
            vals[9 + b] = t ? p : 0.f;
            vals[17 + b] = (float)t;
            sA += t ? 1.f - p : p;
        }
        sumA[pix] = sA;
        vals[0] = bce;
#pragma unroll
        for (int k = 0; k < 25; ++k)
#pragma unroll
            for (int o = 32; o; o >>= 1) vals[k] += __shfl_down(vals[k], o);
        int wave = tid >> 6, lane = tid & 63;
        if (lane == 0)
#pragma unroll
            for (int k = 0; k < 25; ++k) lds[wave][k] = vals[k];
        __syncthreads();
        if (tid < 25) {
            double s = 0.0;
#pragma unroll
            for (int wv = 0; wv < 12; ++wv) s += (double)lds[wv][tid];
            part2[bid * 25 + tid] = s;
        }
    } else if (bid < NFB + NVB) {
        // ---- vertical distance, word-parallel: thread = (32-row word, column) ----
        int vb = bid - NFB;
        int wd = tid >> 6;                 // 0..11
        int wl = tid & 63;
        int b = vb / 6;
        int w = (vb % 6) * 64 + wl;

        const int* colp = tgt + b * HW + w + (wd * 32) * W;
        unsigned m = 0;
#pragma unroll
        for (int i = 0; i < 32; ++i)
            m |= (colp[i * W] != 0) ? (1u << i) : 0u;
        bmsh[wd][wl] = m;
        __syncthreads();

        unsigned mp = m, mn = ~m;
        int dfe_p = INF_I, dfe_n = INF_I, dbe_p = INF_I, dbe_n = INF_I;
        if (wd > 0) {
            int k = wd - 1; unsigned mm;
            while ((mm = bmsh[k][wl]) == 0 && k > 0) --k;
            if (mm) dfe_p = wd * 32 - 1 - (k * 32 + 31 - __clz(mm));
            k = wd - 1;
            while ((mm = ~bmsh[k][wl]) == 0 && k > 0) --k;
            if (mm) dfe_n = wd * 32 - 1 - (k * 32 + 31 - __clz(mm));
        }
        if (wd < 11) {
            int k = wd + 1; unsigned mm;
            while ((mm = bmsh[k][wl]) == 0 && k < 11) ++k;
            if (mm) dbe_p = k * 32 + (__ffs(mm) - 1) - (wd + 1) * 32;
            k = wd + 1;
            while ((mm = ~bmsh[k][wl]) == 0 && k < 11) ++k;
            if (mm) dbe_n = k * 32 + (__ffs(mm) - 1) - (wd + 1) * 32;
        }

        int dfp[32], dfn[32];
        int cp = dfe_p, cn = dfe_n;
#pragma unroll
        for (int i = 0; i < 32; ++i) {
            cp = ((mp >> i) & 1u) ? 0 : min(cp + 1, INF_I);
            cn = ((mn >> i) & 1u) ? 0 : min(cn + 1, INF_I);
            dfp[i] = cp; dfn[i] = cn;
        }
        unsigned* outc = g2u + b * HW + (wd * 32) * W + w;
        cp = dbe_p; cn = dbe_n;
#pragma unroll
        for (int i = 31; i >= 0; --i) {
            cp = ((mp >> i) & 1u) ? 0 : min(cp + 1, INF_I);
            cn = ((mn >> i) & 1u) ? 0 : min(cn + 1, INF_I);
            int dp = min(dfp[i], cp);
            int dn = min(dfn[i], cn);
            outc[i * W] = (unsigned)dp | ((unsigned)dn << 16);
        }
    }

    grid.sync();

    // ================= phase B: row envelope, one row per wave =================
    {
        int wv = tid >> 6, lane = tid & 63;
        int bh = bid * 12 + wv;
        int b = bh / H, h = bh % H;
        const unsigned* row = g2u + b * HW + h * W;
        for (int q = lane; q < W; q += 64) {
            unsigned v = row[q];
            float dp = (float)(v & 0xFFFFu);
            float dn = (float)(v >> 16);
            int s = q + (q >> 4);
            lfp[wv][s] = dp * dp;          // exact: ints <= 1e4 -> d^2 <= 1e8
            lfn[wv][s] = dn * dn;
        }
        // wave-local producer/consumer: all lanes' writes then reads within one wave
        asm volatile("s_waitcnt lgkmcnt(0)" ::: "memory");

        int base = 6 * lane - 8;
        float rp[22], rn[22];
#pragma unroll
        for (int r = 0; r < 22; ++r) {
            int j = base + r;
            j = j < 0 ? 0 : (j > W - 1 ? W - 1 : j);
            int s = j + (j >> 4);
            rp[r] = lfp[wv][s];
            rn[r] = lfn[wv][s];
        }
        const float DD[17] = {64.f,49.f,36.f,25.f,16.f,9.f,4.f,1.f,0.f,
                              1.f,4.f,9.f,16.f,25.f,36.f,49.f,64.f};
        float partial = 0.f;
#pragma unroll
        for (int q = 0; q < 6; ++q) {
            int i = 6 * lane + q;
            float Dp = 3.0e38f, Dn = 3.0e38f;
#pragma unroll
            for (int tt = 0; tt < 17; ++tt) {
                Dp = fminf(Dp, rp[q + tt] + DD[tt]);
                Dn = fminf(Dn, rn[q + tt] + DD[tt]);
            }
            if (Dp > 64.f || Dn > 64.f) {  // exactness not proven -> full row
                float fi = (float)i;
                for (int j = 0; j < W; ++j) {
                    int s = j + (j >> 4);
                    float d = fi - (float)j;
                    Dp = fminf(Dp, fmaf(d, d, lfp[wv][s]));
                    Dn = fminf(Dn, fmaf(d, d, lfn[wv][s]));
                }
            }
            float sdf = fabsf(sqrtf(Dp) - sqrtf(Dn));
            partial += sdf * sumA[h * W + i];
        }
        double v = partial;
#pragma unroll
        for (int o = 32; o; o >>= 1) v += __shfl_down(v, o);
        if (lane == 0) wpart[wv] = v;
        __syncthreads();
        if (tid == 0) {
            double bp = 0.0;
#pragma unroll
            for (int k = 0; k < 12; ++k) bp += wpart[k];
            part[bid] = bp;                // plain store; grid.sync publishes
        }
    }

    grid.sync();

    // ================= phase C: block 0 combines =================
    if (bid == 0) {
        if (tid < 400) {
            int v = tid >> 4, sub = tid & 15;
            double s = 0.0;
            for (int blk = sub; blk < NFB; blk += 16) s += part2[blk * 25 + v];
#pragma unroll
            for (int o = 8; o; o >>= 1) s += __shfl_down(s, o, 16);
            if (sub == 0) sval[v] = s;
        }
        double s2 = 0.0;
        if (tid < 256) s2 = part[tid];
#pragma unroll
        for (int o = 32; o; o >>= 1) s2 += __shfl_down(s2, o);
        if (tid < 256 && (tid & 63) == 0) sl2[tid >> 6] = s2;
        __syncthreads();
        if (tid == 0) {
            double bce = sval[0] / (double)NTOT;
            double dsum = 0.0;
            for (int bb = 0; bb < 8; ++bb)
                dsum += (2.0 * sval[9 + bb] + 1e-5) / (sval[1 + bb] + sval[17 + bb] + 1e-5);
            double dice = dsum / 8.0;
            double loss1 = 0.5 * bce + (1.0 - dice);
            double loss2 = (sl2[0] + sl2[1] + sl2[2] + sl2[3])
                         / ((double)B * (double)B * (double)HW);
            out[0] = (float)(0.7 * loss1 + 0.03 * loss2);
        }
    }
}

extern "C" void kernel_launch(void* const* d_in, const int* in_sizes, int n_in,
                              void* d_out, int out_size, void* d_ws, size_t ws_size,
                              hipStream_t stream) {
    const float* pred = (const float*)d_in[0];
    const int* tgt = (const int*)d_in[1];
    float* out = (float*)d_out;
    char* ws = (char*)d_ws;
    double* part2 = (double*)ws;
    double* part = (double*)(ws + 40960);
    unsigned* g2u = (unsigned*)(ws + 65536);
    float* sumA = (float*)(ws + 4784128);

    void* args[] = {(void*)&pred, (void*)&tgt, (void*)&sumA, (void*)&part2,
                    (void*)&g2u, (void*)&part, (void*)&out};
    hipLaunchCooperativeKernel((const void*)k_coop, dim3(NBLK), dim3(768),
                               args, 0, stream);
}

// Round 10
// 28.897 us; speedup vs baseline: 3.2121x; 3.2121x over previous
//
#include <hip/hip_runtime.h>
#include <math.h>

#define B 8
#define H 384
#define W 384
#define HW (H*W)
#define NTOT (B*HW)
#define INF_I 10000
#define NFB 192            // fused-reduction blocks in stage1
#define NVB 48             // vertical-EDT blocks in stage1
#define NRB 256            // row worker blocks (12 rows = 12 waves each)

// ws layout (bytes):
//   cnt   @ 0      : 64 lines x 256B   (uint counter per line, 4 writers each)
//   slot  @ 16384  : 256 lines x 256B  (ull slot per worker block)
//   part2 @ 81920  : NFB*25 doubles (38400 B)  fused partials
//   g2u   @ 122880 : NTOT uint   (dpos | dneg<<16)
//   sumA  @ 4841472: HW float    (sum_b |p - t|)

// ---------------- launch 1: fused BCE/dice/sumA + vertical EDT ----------------
__global__ __launch_bounds__(768) void k_stage1(const float* __restrict__ pred,
                                                const int* __restrict__ tgt,
                                                float* __restrict__ sumA,
                                                double* __restrict__ part2,
                                                unsigned* __restrict__ g2u,
                                                char* __restrict__ syncws) {
    __shared__ float lds[12][25];
    __shared__ unsigned bmsh[12][64];
    int tid = threadIdx.x;

    if (blockIdx.x < NFB) {
        // ---- fused BCE + dice partials + sumA: one pixel/thread, 8 batches ----
        int pix = blockIdx.x * 768 + tid;
        float vals[25];                    // 0=bce, 1+b=p, 9+b=p*t, 17+b=t
        float sA = 0.f, bce = 0.f;
#pragma unroll
        for (int b = 0; b < 8; ++b) {
            float x = pred[b * HW + pix];
            int t = tgt[b * HW + pix];
            float e = expf(-fabsf(x));
            float r = 1.f / (1.f + e);
            float p = (x >= 0.f) ? r : 1.f - r;                // stable sigmoid
            bce += fmaxf(x, 0.f) + log1pf(e) - x * (float)t;   // softplus - x*t
            vals[1 + b] = p;
            vals[9 + b] = t ? p : 0.f;
            vals[17 + b] = (float)t;
            sA += t ? 1.f - p : p;
        }
        sumA[pix] = sA;
        vals[0] = bce;
#pragma unroll
        for (int k = 0; k < 25; ++k)
#pragma unroll
            for (int o = 32; o; o >>= 1) vals[k] += __shfl_down(vals[k], o);
        int wave = tid >> 6, lane = tid & 63;
        if (lane == 0)
#pragma unroll
            for (int k = 0; k < 25; ++k) lds[wave][k] = vals[k];
        __syncthreads();
        if (tid < 25) {
            double s = 0.0;
#pragma unroll
            for (int wv = 0; wv < 12; ++wv) s += (double)lds[wv][tid];
            part2[blockIdx.x * 25 + tid] = s;
        }
    } else {
        // vert block 0 resets the 64 counter lines (visible to node 2 via boundary)
        if (blockIdx.x == NFB && tid < 64) *(unsigned*)(syncws + tid * 256) = 0u;
        // ---- vertical distance, word-parallel: thread = (32-row word, column) ----
        int vb = blockIdx.x - NFB;
        int wd = tid >> 6;                 // 0..11
        int wl = tid & 63;
        int b = vb / 6;
        int w = (vb % 6) * 64 + wl;

        const int* colp = tgt + b * HW + w + (wd * 32) * W;
        unsigned m = 0;
#pragma unroll
        for (int i = 0; i < 32; ++i)
            m |= (colp[i * W] != 0) ? (1u << i) : 0u;
        bmsh[wd][wl] = m;
        __syncthreads();

        unsigned mp = m, mn = ~m;
        int dfe_p = INF_I, dfe_n = INF_I, dbe_p = INF_I, dbe_n = INF_I;
        if (wd > 0) {
            int k = wd - 1; unsigned mm;
            while ((mm = bmsh[k][wl]) == 0 && k > 0) --k;
            if (mm) dfe_p = wd * 32 - 1 - (k * 32 + 31 - __clz(mm));
            k = wd - 1;
            while ((mm = ~bmsh[k][wl]) == 0 && k > 0) --k;
            if (mm) dfe_n = wd * 32 - 1 - (k * 32 + 31 - __clz(mm));
        }
        if (wd < 11) {
            int k = wd + 1; unsigned mm;
            while ((mm = bmsh[k][wl]) == 0 && k < 11) ++k;
            if (mm) dbe_p = k * 32 + (__ffs(mm) - 1) - (wd + 1) * 32;
            k = wd + 1;
            while ((mm = ~bmsh[k][wl]) == 0 && k < 11) ++k;
            if (mm) dbe_n = k * 32 + (__ffs(mm) - 1) - (wd + 1) * 32;
        }

        int dfp[32], dfn[32];
        int cp = dfe_p, cn = dfe_n;
#pragma unroll
        for (int i = 0; i < 32; ++i) {
            cp = ((mp >> i) & 1u) ? 0 : min(cp + 1, INF_I);
            cn = ((mn >> i) & 1u) ? 0 : min(cn + 1, INF_I);
            dfp[i] = cp; dfn[i] = cn;
        }
        unsigned* outc = g2u + b * HW + (wd * 32) * W + w;
        cp = dbe_p; cn = dbe_n;
#pragma unroll
        for (int i = 31; i >= 0; --i) {
            cp = ((mp >> i) & 1u) ? 0 : min(cp + 1, INF_I);
            cn = ((mn >> i) & 1u) ? 0 : min(cn + 1, INF_I);
            int dp = min(dfp[i], cp);
            int dn = min(dfn[i], cn);
            outc[i * W] = (unsigned)dp | ((unsigned)dn << 16);
        }
    }
}

// ---------------- launch 2: row envelope (workers) + parallel-poll combiner ----------------
__global__ __launch_bounds__(768) void k_rows(const unsigned* __restrict__ g2u,
                                              const float* __restrict__ sumA,
                                              const double* __restrict__ part2,
                                              char* __restrict__ syncws,
                                              float* __restrict__ out) {
    __shared__ float lfp[12][412], lfn[12][412];
    __shared__ double wpart[12];
    __shared__ double sval[25];
    int tid = threadIdx.x, bid = blockIdx.x;

    if (bid == NRB) {
        // ================= combiner block =================
        // loss1 partial reduction first (plain loads, node-boundary coherent)
        if (tid < 400) {
            int v = tid >> 4, sub = tid & 15;
            double s = 0.0;
            for (int blk = sub; blk < NFB; blk += 16) s += part2[blk * 25 + v];
#pragma unroll
            for (int o = 8; o; o >>= 1) s += __shfl_down(s, o, 16);
            if (sub == 0) sval[v] = s;
        }
        __syncthreads();
        double s2 = 0.0;
        if (tid < 64) {
            // parallel poll: lane l owns counter line l (4 workers each)
            unsigned c;
            do {
                c = atomicAdd((unsigned*)(syncws + tid * 256), 0u);
                if (__all(c == 4u)) break;
                __builtin_amdgcn_s_sleep(1);
            } while (1);
            // gather 4 slots per lane (independent atomic loads, fixed order)
            double r0 = __longlong_as_double(atomicAdd(
                (unsigned long long*)(syncws + 16384 + (0 * 64 + tid) * 256), 0ull));
            double r1 = __longlong_as_double(atomicAdd(
                (unsigned long long*)(syncws + 16384 + (1 * 64 + tid) * 256), 0ull));
            double r2 = __longlong_as_double(atomicAdd(
                (unsigned long long*)(syncws + 16384 + (2 * 64 + tid) * 256), 0ull));
            double r3 = __longlong_as_double(atomicAdd(
                (unsigned long long*)(syncws + 16384 + (3 * 64 + tid) * 256), 0ull));
            s2 = ((r0 + r1) + r2) + r3;
#pragma unroll
            for (int o = 32; o; o >>= 1) s2 += __shfl_down(s2, o);
        }
        if (tid == 0) {
            double bce = sval[0] / (double)NTOT;
            double dsum = 0.0;
            for (int bb = 0; bb < 8; ++bb)
                dsum += (2.0 * sval[9 + bb] + 1e-5) / (sval[1 + bb] + sval[17 + bb] + 1e-5);
            double dice = dsum / 8.0;
            double loss1 = 0.5 * bce + (1.0 - dice);
            double loss2 = s2 / ((double)B * (double)B * (double)HW);
            out[0] = (float)(0.7 * loss1 + 0.03 * loss2);
        }
        return;
    }

    // ================= worker block: 12 rows, one per wave =================
    int wv = tid >> 6, lane = tid & 63;
    int bh = bid * 12 + wv;
    int b = bh / H, h = bh % H;
    const unsigned* row = g2u + b * HW + h * W;
    for (int q = lane; q < W; q += 64) {
        unsigned v = row[q];
        float dp = (float)(v & 0xFFFFu);
        float dn = (float)(v >> 16);
        int s = q + (q >> 4);
        lfp[wv][s] = dp * dp;              // exact: ints <= 1e4 -> d^2 <= 1e8
        lfn[wv][s] = dn * dn;
    }
    // wave-local producer/consumer: this wave only reads its own rows
    asm volatile("s_waitcnt lgkmcnt(0)" ::: "memory");

    int base = 6 * lane - 8;
    float rp[22], rn[22];
#pragma unroll
    for (int r = 0; r < 22; ++r) {
        int j = base + r;
        j = j < 0 ? 0 : (j > W - 1 ? W - 1 : j);
        int s = j + (j >> 4);
        rp[r] = lfp[wv][s];
        rn[r] = lfn[wv][s];
    }
    const float DD[17] = {64.f,49.f,36.f,25.f,16.f,9.f,4.f,1.f,0.f,
                          1.f,4.f,9.f,16.f,25.f,36.f,49.f,64.f};
    float partial = 0.f;
#pragma unroll
    for (int q = 0; q < 6; ++q) {
        int i = 6 * lane + q;
        float Dp = 3.0e38f, Dn = 3.0e38f;
#pragma unroll
        for (int tt = 0; tt < 17; ++tt) {
            Dp = fminf(Dp, rp[q + tt] + DD[tt]);
            Dn = fminf(Dn, rn[q + tt] + DD[tt]);
        }
        if (Dp > 64.f || Dn > 64.f) {      // exactness not proven -> full row
            float fi = (float)i;
            for (int j = 0; j < W; ++j) {
                int s = j + (j >> 4);
                float d = fi - (float)j;
                Dp = fminf(Dp, fmaf(d, d, lfp[wv][s]));
                Dn = fminf(Dn, fmaf(d, d, lfn[wv][s]));
            }
        }
        float sdf = fabsf(sqrtf(Dp) - sqrtf(Dn));
        partial += sdf * sumA[h * W + i];
    }
    double v = partial;
#pragma unroll
    for (int o = 32; o; o >>= 1) v += __shfl_down(v, o);
    if (lane == 0) wpart[wv] = v;
    __syncthreads();

    if (tid == 0) {
        double bp = 0.0;
#pragma unroll
        for (int k = 0; k < 12; ++k) bp += wpart[k];
        // private slot (atomicExch: deterministic, single writer), then signal.
        atomicExch((unsigned long long*)(syncws + 16384 + bid * 256),
                   __double_as_longlong(bp));
        asm volatile("s_waitcnt vmcnt(0)" ::: "memory");   // slot visible before cnt
        atomicAdd((unsigned*)(syncws + (bid >> 2) * 256), 1u);
    }
}

extern "C" void kernel_launch(void* const* d_in, const int* in_sizes, int n_in,
                              void* d_out, int out_size, void* d_ws, size_t ws_size,
                              hipStream_t stream) {
    const float* pred = (const float*)d_in[0];
    const int* tgt = (const int*)d_in[1];
    float* out = (float*)d_out;
    char* ws = (char*)d_ws;
    char* syncws = ws;
    double* part2 = (double*)(ws + 81920);
    unsigned* g2u = (unsigned*)(ws + 122880);
    float* sumA = (float*)(ws + 4841472);

    k_stage1<<<NFB + NVB, 768, 0, stream>>>(pred, tgt, sumA, part2, g2u, syncws);
    k_rows<<<NRB + 1, 768, 0, stream>>>(g2u, sumA, part2, syncws, out);
}